// Round 5
// baseline (266.193 us; speedup 1.0000x reference)
//
#include <hip/hip_runtime.h>

// MPS tensor-train classifier, B=16384, D=784, BOND=5, OUT=10.
//
// Round-8: round-7's scalar-coefficient structure (44 VGPR, no spills,
// no pk LDS traffic) was issue/stall-bound at 4 waves/SIMD (VALUBusy 44%,
// dur invariant across LDS vs SGPR coefficient paths). This round doubles
// occupancy and halves per-wave chain length: chain split in two halves
// across 2x blocks (round-6's split topology, but 1 row/lane so no
// dual-row register blowup).
//   512 blocks x 1024 thr; block = {row-group g (64 rows), half h}.
//   h=0: wave 0 = carry0+site0+pairs 0..14; waves 1..15 = 12-pair matrix
//        products (pairs 15..194); combine -> vL -> out-flat[0:81920).
//   h=1: wave 0 = vlast+site781+pairs 389..375 desc (transposed storage);
//        waves 1..15 = pairs 195..374; combine desc -> wR -> out-flat
//        [81920:163840).
//   finish_dot: res = vL.wR -> ws (dead pk region). finish_out: out =
//   res*fc_w + fc_b.
// __launch_bounds__(1024,8) caps VGPR at 64 (round-7 used 44) -> 2 blocks/
// CU = 8 waves/SIMD; LDS 51.2 KB/block -> 102.4 KB/CU, fits 160.
//
// pk layout (100 floats/pair), q = 0..3 (coeff of 1, xa, xb, xa*xb):
//   rows:  q*20 + l*4 + r   (l=0..4, r=0..3)      -> s4[q*5 + l]
//   col4:  80 + l*4 + q     (l=0..3, q=0..3)      -> s4[20 + l]  (l-major)
//   (4,4): 96 + q                                  -> s4[24]

typedef float v4f __attribute__((ext_vector_type(4)));
typedef float v2f __attribute__((ext_vector_type(2)));

constexpr int Bn     = 16384;
constexpr int Dn     = 784;
constexpr int NOUT   = 10;
constexpr int NPAIR  = 390;   // pairs cover sites 1..780
constexpr int PVEC   = 15;    // vec-wave pairs per half
constexpr int PMAT   = 12;    // pairs per matrix wave (15 waves per half)
constexpr int RHP0   = 195;   // right half first pair
constexpr int BWD_P0 = 375;   // pairs >= this stored transposed (right vec)
constexpr int PAIR_F = 100;   // floats per pair block
constexpr int WROFF  = Bn * 5; // wR stash offset (floats) in out

__device__ __forceinline__ v4f splat4(float x) { v4f v = {x, x, x, x}; return v; }
__device__ __forceinline__ v4f fma4(v4f a, v4f b, v4f c) {
    return __builtin_elementwise_fma(a, b, c);
}

struct Frag { v4f r[5]; float c4[5]; };          // 5x5 running product

// T = M @ C(s; xa,xb), l-major: C row l built from uniform (SGPR)
// coefficients and immediately consumed.
__device__ __forceinline__ void matstepLM(const Frag& M, Frag& T,
                                          const float* __restrict__ s, v2f xc) {
    const float xa = xc[0], xb = xc[1], xab = xa * xb;
    const v4f va = splat4(xa), vb = splat4(xb), vp = splat4(xab);
    const v4f* s4 = (const v4f*)s;
#pragma unroll
    for (int l = 0; l < 5; ++l) {
        v4f crow = fma4(vp, s4[15 + l], fma4(vb, s4[10 + l], fma4(va, s4[5 + l], s4[l])));
        v4f cq = (l < 4) ? s4[20 + l] : s4[24];
        float c4l = fmaf(xab, cq[3], fmaf(xb, cq[2], fmaf(xa, cq[1], cq[0])));
#pragma unroll
        for (int i = 0; i < 5; ++i) {
            float mil = (l < 4) ? M.r[i][l] : M.c4[i];
            if (l == 0) {
                T.r[i]  = splat4(mil) * crow;
                T.c4[i] = mil * c4l;
            } else {
                T.r[i]  = fma4(splat4(mil), crow, T.r[i]);
                T.c4[i] = fmaf(mil, c4l, T.c4[i]);
            }
        }
    }
}

// c' = c @ C (row vector), l-major
__device__ __forceinline__ void vecstepLM(v4f& cv, float& c4,
                                          const float* __restrict__ s, v2f xc) {
    const float xa = xc[0], xb = xc[1], xab = xa * xb;
    const v4f va = splat4(xa), vb = splat4(xb), vp = splat4(xab);
    const v4f* s4 = (const v4f*)s;
    v4f acc; float a4;
#pragma unroll
    for (int l = 0; l < 5; ++l) {
        v4f crow = fma4(vp, s4[15 + l], fma4(vb, s4[10 + l], fma4(va, s4[5 + l], s4[l])));
        v4f cq = (l < 4) ? s4[20 + l] : s4[24];
        float c4l = fmaf(xab, cq[3], fmaf(xb, cq[2], fmaf(xa, cq[1], cq[0])));
        float cl = (l < 4) ? cv[l] : c4;
        if (l == 0) { acc = splat4(cl) * crow; a4 = cl * c4l; }
        else        { acc = fma4(splat4(cl), crow, acc); a4 = fmaf(cl, c4l, a4); }
    }
    cv = acc; c4 = a4;
}

// ---- prepack: build pair blocks (transposed for p >= BWD_P0) ----
// cores_mid element (m,l,i,k) at (m*5+l)*10 + i*5 + k
__global__ void prepack_pairs(const float* __restrict__ cm, float* __restrict__ pk)
{
    int idx = blockIdx.x * 256 + threadIdx.x;
    if (idx >= NPAIR * 100) return;
    int p = idx / 100, rest = idx - p * 100;
    int q = rest / 25, e = rest - q * 25;
    int l = e / 5, r = e - l * 5;
    int m1 = 2 * p + 1, m2 = 2 * p + 2;
    const float* L = cm + (size_t)(m1 * 5 + l) * 10;
    float acc = 0.f;
#pragma unroll
    for (int k = 0; k < 5; ++k) {
        float Lk = (q & 1) ? (L[5 + k] - L[k]) : L[k];
        const float* R = cm + (size_t)(m2 * 5 + k) * 10;
        float Rk = (q & 2) ? (R[5 + r] - R[r]) : R[r];
        acc = fmaf(Lk, Rk, acc);
    }
    int wl = l, wr = r;
    if (p >= BWD_P0) { wl = r; wr = l; }   // store C^T for right vec wave
    int off;
    if (wr < 4)      off = q * 20 + wl * 4 + wr;
    else if (wl < 4) off = 80 + wl * 4 + q;   // col4, l-major
    else             off = 96 + q;            // c44 quad
    pk[(size_t)p * PAIR_F + off] = acc;
}

__global__ __launch_bounds__(1024, 8)
void mps_half_kernel(const float* __restrict__ x,          // [B, D]
                     const float* __restrict__ core_first, // [2,5]
                     const float* __restrict__ cores_mid,  // [782,5,2,5]
                     const float* __restrict__ core_last,  // [5,2]
                     const float* __restrict__ pk,         // [390][100]
                     float* __restrict__ out)              // [B,10] used as stash
{
    __shared__ float matbuf[8][25][64];   // 51.2 KB combine matrices

    const int lane = threadIdx.x & 63;
    const int wave = threadIdx.x >> 6;
    const int wu   = __builtin_amdgcn_readfirstlane(wave);  // uniform wave id
    const int g    = blockIdx.x >> 1;
    const int h    = blockIdx.x & 1;
    const int row  = g * 64 + lane;
    const float* __restrict__ xr = x + (size_t)row * Dn;
    const v2f* __restrict__ xr2 = (const v2f*)xr;          // 392 entries

    if (wu >= 1) {
        // ---- matrix wave: 12 pairs, scalar-coefficient matsteps ----
        const int p0 = (h == 0 ? PVEC : RHP0) + PMAT * (wu - 1);  // uniform

        Frag M, T;
        M.r[0] = {1,0,0,0}; M.r[1] = {0,1,0,0}; M.r[2] = {0,0,1,0};
        M.r[3] = {0,0,0,1}; M.r[4] = {0,0,0,0};
        M.c4[0] = 0; M.c4[1] = 0; M.c4[2] = 0; M.c4[3] = 0; M.c4[4] = 1;

        v2f x0 = xr2[p0 + 1], x1 = xr2[p0 + 2];
#pragma unroll 1
        for (int j = 0; j < PMAT; j += 2) {
            const float* s0 = pk + (size_t)(p0 + j) * PAIR_F;  // uniform addr
            v2f nx0 = xr2[p0 + j + 3], nx1 = xr2[p0 + j + 4];  // x prefetch
            matstepLM(M, T, s0, x0);
            matstepLM(T, M, s0 + PAIR_F, x1);
            x0 = nx0; x1 = nx1;
        }

        // slot phase/index: left vec consumes slots ascending (1..15),
        // right vec descending (15..1); phase-1 = first 8 consumed.
        const bool ph1 = (h == 0) ? (wu <= 8) : (wu >= 8);
        const int  k   = (h == 0) ? (ph1 ? wu - 1 : wu - 9)
                                  : (ph1 ? 15 - wu : 7 - wu);
        if (ph1) {
#pragma unroll
            for (int i = 0; i < 5; ++i) {
#pragma unroll
                for (int r = 0; r < 4; ++r) matbuf[k][i * 5 + r][lane] = M.r[i][r];
                matbuf[k][i * 5 + 4][lane] = M.c4[i];
            }
        }
        __syncthreads();   // b1: phase-1 slots ready
        __syncthreads();   // b2: vec finished reading phase-1
        if (!ph1) {
#pragma unroll
            for (int i = 0; i < 5; ++i) {
#pragma unroll
                for (int r = 0; r < 4; ++r) matbuf[k][i * 5 + r][lane] = M.r[i][r];
                matbuf[k][i * 5 + 4][lane] = M.c4[i];
            }
        }
        __syncthreads();   // b3: phase-2 slots ready
    } else if (h == 0) {
        // ---- left vec wave: carry0, site 0, pairs 0..14, combine asc ----
        v2f x01 = xr2[0];
        float cl[5], cn[5];
#pragma unroll
        for (int r = 0; r < 5; ++r)
            cl[r] = fmaf(x01[0], core_first[5 + r] - core_first[r], core_first[r]);
        const float* cm0 = cores_mid;                      // site 0
#pragma unroll
        for (int r = 0; r < 5; ++r) {
            float a = 0.f;
#pragma unroll
            for (int l = 0; l < 5; ++l) {
                float m = fmaf(x01[1], cm0[l * 10 + 5 + r] - cm0[l * 10 + r], cm0[l * 10 + r]);
                a = fmaf(cl[l], m, a);
            }
            cn[r] = a;
        }
        v4f cv = {cn[0], cn[1], cn[2], cn[3]};
        float c4 = cn[4];

        v2f xc = xr2[1];
#pragma unroll 1
        for (int p = 0; p < PVEC; ++p) {
            v2f nx = xr2[p + 2];
            vecstepLM(cv, c4, pk + (size_t)p * PAIR_F, xc);
            xc = nx;
        }
        cl[0] = cv[0]; cl[1] = cv[1]; cl[2] = cv[2]; cl[3] = cv[3]; cl[4] = c4;

        __syncthreads();   // b1: phase-1 slots (waves 1..8 at k=0..7)
#pragma unroll 1
        for (int k = 0; k < 8; ++k) {
            float v0[5];
#pragma unroll
            for (int r = 0; r < 5; ++r) v0[r] = cl[0] * matbuf[k][r][lane];
#pragma unroll
            for (int l = 1; l < 5; ++l)
#pragma unroll
                for (int r = 0; r < 5; ++r)
                    v0[r] = fmaf(cl[l], matbuf[k][l * 5 + r][lane], v0[r]);
#pragma unroll
            for (int r = 0; r < 5; ++r) cl[r] = v0[r];
        }
        __syncthreads();   // b2
        __syncthreads();   // b3: phase-2 slots (waves 9..15 at k=0..6)
#pragma unroll 1
        for (int k = 0; k < 7; ++k) {
            float v0[5];
#pragma unroll
            for (int r = 0; r < 5; ++r) v0[r] = cl[0] * matbuf[k][r][lane];
#pragma unroll
            for (int l = 1; l < 5; ++l)
#pragma unroll
                for (int r = 0; r < 5; ++r)
                    v0[r] = fmaf(cl[l], matbuf[k][l * 5 + r][lane], v0[r]);
#pragma unroll
            for (int r = 0; r < 5; ++r) cl[r] = v0[r];
        }
        float* o = out + (size_t)row * 5;                  // vL stash (flat)
#pragma unroll
        for (int i = 0; i < 5; ++i) o[i] = cl[i];
    } else {
        // ---- right vec wave: vlast, site 781, pairs 389..375 desc,
        //      combine desc (slots 15..1, column form) ----
        v2f xz = xr2[391];                                 // {x782, x783}
        float vl[5], vn[5];
#pragma unroll
        for (int l = 0; l < 5; ++l)
            vl[l] = fmaf(xz[1], core_last[2 * l + 1] - core_last[2 * l], core_last[2 * l]);
        const float* cmL = cores_mid + (size_t)781 * 50;
#pragma unroll
        for (int l = 0; l < 5; ++l) {
            float a = 0.f;
#pragma unroll
            for (int r = 0; r < 5; ++r) {
                float m = fmaf(xz[0], cmL[l * 10 + 5 + r] - cmL[l * 10 + r], cmL[l * 10 + r]);
                a = fmaf(m, vl[r], a);
            }
            vn[l] = a;
        }
        v4f cv = {vn[0], vn[1], vn[2], vn[3]};
        float c4 = vn[4];

        v2f xc = xr2[390];
#pragma unroll 1
        for (int p = 389; p >= BWD_P0; --p) {              // transposed storage
            v2f nx = xr2[p];                               // x for pair p-1
            vecstepLM(cv, c4, pk + (size_t)p * PAIR_F, xc);
            xc = nx;
        }
        float u[5] = {cv[0], cv[1], cv[2], cv[3], c4};

        __syncthreads();   // b1: phase-1 slots (waves 15..8 at k=0..7)
#pragma unroll 1
        for (int k = 0; k < 8; ++k) {                      // u = M_slot @ u
            float v0[5];
#pragma unroll
            for (int i = 0; i < 5; ++i) {
                float a = matbuf[k][i * 5][lane] * u[0];
#pragma unroll
                for (int l = 1; l < 5; ++l)
                    a = fmaf(matbuf[k][i * 5 + l][lane], u[l], a);
                v0[i] = a;
            }
#pragma unroll
            for (int i = 0; i < 5; ++i) u[i] = v0[i];
        }
        __syncthreads();   // b2
        __syncthreads();   // b3: phase-2 slots (waves 7..1 at k=0..6)
#pragma unroll 1
        for (int k = 0; k < 7; ++k) {
            float v0[5];
#pragma unroll
            for (int i = 0; i < 5; ++i) {
                float a = matbuf[k][i * 5][lane] * u[0];
#pragma unroll
                for (int l = 1; l < 5; ++l)
                    a = fmaf(matbuf[k][i * 5 + l][lane], u[l], a);
                v0[i] = a;
            }
#pragma unroll
            for (int i = 0; i < 5; ++i) u[i] = v0[i];
        }
        float* o = out + WROFF + (size_t)row * 5;          // wR stash (flat)
#pragma unroll
        for (int i = 0; i < 5; ++i) o[i] = u[i];
    }
}

// ---- stage 2a: res[r] = vL . wR (res overwrites dead pk region of ws) ----
__global__ __launch_bounds__(256)
void finish_dot(const float* __restrict__ outF, float* __restrict__ res)
{
    int r = blockIdx.x * 256 + threadIdx.x;
    const float* vl = outF + (size_t)r * 5;
    const float* wr = outF + WROFF + (size_t)r * 5;
    float s = vl[0] * wr[0];
#pragma unroll
    for (int i = 1; i < 5; ++i) s = fmaf(vl[i], wr[i], s);
    res[r] = s;
}

// ---- stage 2b: out = res*fc_w + fc_b ----
__global__ __launch_bounds__(256)
void finish_out(const float* __restrict__ res, const float* __restrict__ fc_w,
                const float* __restrict__ fc_b, float* __restrict__ out)
{
    int r = blockIdx.x * 256 + threadIdx.x;
    float rv = res[r];
    float* o = out + (size_t)r * NOUT;
#pragma unroll
    for (int j = 0; j < NOUT; ++j) o[j] = fmaf(rv, fc_w[j], fc_b[j]);
}

extern "C" void kernel_launch(void* const* d_in, const int* in_sizes, int n_in,
                              void* d_out, int out_size, void* d_ws, size_t ws_size,
                              hipStream_t stream) {
    const float* x          = (const float*)d_in[0];
    const float* core_first = (const float*)d_in[1];
    const float* cores_mid  = (const float*)d_in[2];
    const float* core_last  = (const float*)d_in[3];
    const float* fc_w       = (const float*)d_in[4];
    const float* fc_b       = (const float*)d_in[5];
    float* out              = (float*)d_out;
    float* pk               = (float*)d_ws;   // 390*100*4 = 156,000 B
    float* res              = (float*)d_ws;   // reuses pk region (dead after main)

    hipLaunchKernelGGL(prepack_pairs, dim3((NPAIR * 100 + 255) / 256), dim3(256),
                       0, stream, cores_mid, pk);
    hipLaunchKernelGGL(mps_half_kernel, dim3(512), dim3(1024), 0, stream,
                       x, core_first, cores_mid, core_last, pk, out);
    hipLaunchKernelGGL(finish_dot, dim3(Bn / 256), dim3(256), 0, stream,
                       out, res);
    hipLaunchKernelGGL(finish_out, dim3(Bn / 256), dim3(256), 0, stream,
                       res, fc_w, fc_b, out);
}

// Round 6
// 128.914 us; speedup vs baseline: 2.0649x; 2.0649x over previous
//
#include <hip/hip_runtime.h>

// MPS tensor-train classifier, B=16384, D=784, BOND=5, OUT=10.
//
// Round-9 = round-8's split topology + round-7's launch bounds.
// Round-8 post-mortem: __launch_bounds__(1024,8) made the allocator target
// 32 VGPRs (< the ~50-float Frag M,T live set) -> 342 MB scratch writes,
// 179 us. The SPLIT itself worked (occupancy 37->77%). Round-7 proved the
// same wave bodies compile to 44 VGPR under (1024,4). Min-waves is only an
// allocator floor; with ~44 VGPR and 51.2 KB LDS the hardware fits
// 2 blocks/CU = 8 waves/SIMD on the 512-block grid anyway.
//
//   512 blocks x 1024 thr; block = {row-group g (64 rows), half h}.
//   h=0: wave 0 = carry0+site0+pairs 0..14; waves 1..15 = 12-pair matrix
//        products (pairs 15..194); combine -> vL -> out-flat[0:81920).
//   h=1: wave 0 = vlast+site781+pairs 389..375 desc (transposed storage);
//        waves 1..15 = pairs 195..374; combine desc -> wR.
//   finish_dot: res = vL.wR -> ws (dead pk region). finish_out: out =
//   res*fc_w + fc_b.
//
// pk layout (100 floats/pair), q = 0..3 (coeff of 1, xa, xb, xa*xb):
//   rows:  q*20 + l*4 + r   (l=0..4, r=0..3)      -> s4[q*5 + l]
//   col4:  80 + l*4 + q     (l=0..3, q=0..3)      -> s4[20 + l]  (l-major)
//   (4,4): 96 + q                                  -> s4[24]

typedef float v4f __attribute__((ext_vector_type(4)));
typedef float v2f __attribute__((ext_vector_type(2)));

constexpr int Bn     = 16384;
constexpr int Dn     = 784;
constexpr int NOUT   = 10;
constexpr int NPAIR  = 390;   // pairs cover sites 1..780
constexpr int PVEC   = 15;    // vec-wave pairs per half
constexpr int PMAT   = 12;    // pairs per matrix wave (15 waves per half)
constexpr int RHP0   = 195;   // right half first pair
constexpr int BWD_P0 = 375;   // pairs >= this stored transposed (right vec)
constexpr int PAIR_F = 100;   // floats per pair block
constexpr int WROFF  = Bn * 5; // wR stash offset (floats) in out

__device__ __forceinline__ v4f splat4(float x) { v4f v = {x, x, x, x}; return v; }
__device__ __forceinline__ v4f fma4(v4f a, v4f b, v4f c) {
    return __builtin_elementwise_fma(a, b, c);
}

struct Frag { v4f r[5]; float c4[5]; };          // 5x5 running product

// T = M @ C(s; xa,xb), l-major: C row l built from uniform (SGPR)
// coefficients and immediately consumed.
__device__ __forceinline__ void matstepLM(const Frag& M, Frag& T,
                                          const float* __restrict__ s, v2f xc) {
    const float xa = xc[0], xb = xc[1], xab = xa * xb;
    const v4f va = splat4(xa), vb = splat4(xb), vp = splat4(xab);
    const v4f* s4 = (const v4f*)s;
#pragma unroll
    for (int l = 0; l < 5; ++l) {
        v4f crow = fma4(vp, s4[15 + l], fma4(vb, s4[10 + l], fma4(va, s4[5 + l], s4[l])));
        v4f cq = (l < 4) ? s4[20 + l] : s4[24];
        float c4l = fmaf(xab, cq[3], fmaf(xb, cq[2], fmaf(xa, cq[1], cq[0])));
#pragma unroll
        for (int i = 0; i < 5; ++i) {
            float mil = (l < 4) ? M.r[i][l] : M.c4[i];
            if (l == 0) {
                T.r[i]  = splat4(mil) * crow;
                T.c4[i] = mil * c4l;
            } else {
                T.r[i]  = fma4(splat4(mil), crow, T.r[i]);
                T.c4[i] = fmaf(mil, c4l, T.c4[i]);
            }
        }
    }
}

// c' = c @ C (row vector), l-major
__device__ __forceinline__ void vecstepLM(v4f& cv, float& c4,
                                          const float* __restrict__ s, v2f xc) {
    const float xa = xc[0], xb = xc[1], xab = xa * xb;
    const v4f va = splat4(xa), vb = splat4(xb), vp = splat4(xab);
    const v4f* s4 = (const v4f*)s;
    v4f acc; float a4;
#pragma unroll
    for (int l = 0; l < 5; ++l) {
        v4f crow = fma4(vp, s4[15 + l], fma4(vb, s4[10 + l], fma4(va, s4[5 + l], s4[l])));
        v4f cq = (l < 4) ? s4[20 + l] : s4[24];
        float c4l = fmaf(xab, cq[3], fmaf(xb, cq[2], fmaf(xa, cq[1], cq[0])));
        float cl = (l < 4) ? cv[l] : c4;
        if (l == 0) { acc = splat4(cl) * crow; a4 = cl * c4l; }
        else        { acc = fma4(splat4(cl), crow, acc); a4 = fmaf(cl, c4l, a4); }
    }
    cv = acc; c4 = a4;
}

// ---- prepack: build pair blocks (transposed for p >= BWD_P0) ----
// cores_mid element (m,l,i,k) at (m*5+l)*10 + i*5 + k
__global__ void prepack_pairs(const float* __restrict__ cm, float* __restrict__ pk)
{
    int idx = blockIdx.x * 256 + threadIdx.x;
    if (idx >= NPAIR * 100) return;
    int p = idx / 100, rest = idx - p * 100;
    int q = rest / 25, e = rest - q * 25;
    int l = e / 5, r = e - l * 5;
    int m1 = 2 * p + 1, m2 = 2 * p + 2;
    const float* L = cm + (size_t)(m1 * 5 + l) * 10;
    float acc = 0.f;
#pragma unroll
    for (int k = 0; k < 5; ++k) {
        float Lk = (q & 1) ? (L[5 + k] - L[k]) : L[k];
        const float* R = cm + (size_t)(m2 * 5 + k) * 10;
        float Rk = (q & 2) ? (R[5 + r] - R[r]) : R[r];
        acc = fmaf(Lk, Rk, acc);
    }
    int wl = l, wr = r;
    if (p >= BWD_P0) { wl = r; wr = l; }   // store C^T for right vec wave
    int off;
    if (wr < 4)      off = q * 20 + wl * 4 + wr;
    else if (wl < 4) off = 80 + wl * 4 + q;   // col4, l-major
    else             off = 96 + q;            // c44 quad
    pk[(size_t)p * PAIR_F + off] = acc;
}

__global__ __launch_bounds__(1024, 4)
void mps_half_kernel(const float* __restrict__ x,          // [B, D]
                     const float* __restrict__ core_first, // [2,5]
                     const float* __restrict__ cores_mid,  // [782,5,2,5]
                     const float* __restrict__ core_last,  // [5,2]
                     const float* __restrict__ pk,         // [390][100]
                     float* __restrict__ out)              // [B,10] used as stash
{
    __shared__ float matbuf[8][25][64];   // 51.2 KB combine matrices

    const int lane = threadIdx.x & 63;
    const int wave = threadIdx.x >> 6;
    const int wu   = __builtin_amdgcn_readfirstlane(wave);  // uniform wave id
    const int g    = blockIdx.x >> 1;
    const int h    = blockIdx.x & 1;
    const int row  = g * 64 + lane;
    const float* __restrict__ xr = x + (size_t)row * Dn;
    const v2f* __restrict__ xr2 = (const v2f*)xr;          // 392 entries

    if (wu >= 1) {
        // ---- matrix wave: 12 pairs, scalar-coefficient matsteps ----
        const int p0 = (h == 0 ? PVEC : RHP0) + PMAT * (wu - 1);  // uniform

        Frag M, T;
        M.r[0] = {1,0,0,0}; M.r[1] = {0,1,0,0}; M.r[2] = {0,0,1,0};
        M.r[3] = {0,0,0,1}; M.r[4] = {0,0,0,0};
        M.c4[0] = 0; M.c4[1] = 0; M.c4[2] = 0; M.c4[3] = 0; M.c4[4] = 1;

        v2f x0 = xr2[p0 + 1], x1 = xr2[p0 + 2];
#pragma unroll 1
        for (int j = 0; j < PMAT; j += 2) {
            const float* s0 = pk + (size_t)(p0 + j) * PAIR_F;  // uniform addr
            v2f nx0 = xr2[p0 + j + 3], nx1 = xr2[p0 + j + 4];  // x prefetch
            matstepLM(M, T, s0, x0);
            matstepLM(T, M, s0 + PAIR_F, x1);
            x0 = nx0; x1 = nx1;
        }

        // slot phase/index: left vec consumes slots ascending (1..15),
        // right vec descending (15..1); phase-1 = first 8 consumed.
        const bool ph1 = (h == 0) ? (wu <= 8) : (wu >= 8);
        const int  k   = (h == 0) ? (ph1 ? wu - 1 : wu - 9)
                                  : (ph1 ? 15 - wu : 7 - wu);
        if (ph1) {
#pragma unroll
            for (int i = 0; i < 5; ++i) {
#pragma unroll
                for (int r = 0; r < 4; ++r) matbuf[k][i * 5 + r][lane] = M.r[i][r];
                matbuf[k][i * 5 + 4][lane] = M.c4[i];
            }
        }
        __syncthreads();   // b1: phase-1 slots ready
        __syncthreads();   // b2: vec finished reading phase-1
        if (!ph1) {
#pragma unroll
            for (int i = 0; i < 5; ++i) {
#pragma unroll
                for (int r = 0; r < 4; ++r) matbuf[k][i * 5 + r][lane] = M.r[i][r];
                matbuf[k][i * 5 + 4][lane] = M.c4[i];
            }
        }
        __syncthreads();   // b3: phase-2 slots ready
    } else if (h == 0) {
        // ---- left vec wave: carry0, site 0, pairs 0..14, combine asc ----
        v2f x01 = xr2[0];
        float cl[5], cn[5];
#pragma unroll
        for (int r = 0; r < 5; ++r)
            cl[r] = fmaf(x01[0], core_first[5 + r] - core_first[r], core_first[r]);
        const float* cm0 = cores_mid;                      // site 0
#pragma unroll
        for (int r = 0; r < 5; ++r) {
            float a = 0.f;
#pragma unroll
            for (int l = 0; l < 5; ++l) {
                float m = fmaf(x01[1], cm0[l * 10 + 5 + r] - cm0[l * 10 + r], cm0[l * 10 + r]);
                a = fmaf(cl[l], m, a);
            }
            cn[r] = a;
        }
        v4f cv = {cn[0], cn[1], cn[2], cn[3]};
        float c4 = cn[4];

        v2f xc = xr2[1];
#pragma unroll 1
        for (int p = 0; p < PVEC; ++p) {
            v2f nx = xr2[p + 2];
            vecstepLM(cv, c4, pk + (size_t)p * PAIR_F, xc);
            xc = nx;
        }
        cl[0] = cv[0]; cl[1] = cv[1]; cl[2] = cv[2]; cl[3] = cv[3]; cl[4] = c4;

        __syncthreads();   // b1: phase-1 slots (waves 1..8 at k=0..7)
#pragma unroll 1
        for (int k = 0; k < 8; ++k) {
            float v0[5];
#pragma unroll
            for (int r = 0; r < 5; ++r) v0[r] = cl[0] * matbuf[k][r][lane];
#pragma unroll
            for (int l = 1; l < 5; ++l)
#pragma unroll
                for (int r = 0; r < 5; ++r)
                    v0[r] = fmaf(cl[l], matbuf[k][l * 5 + r][lane], v0[r]);
#pragma unroll
            for (int r = 0; r < 5; ++r) cl[r] = v0[r];
        }
        __syncthreads();   // b2
        __syncthreads();   // b3: phase-2 slots (waves 9..15 at k=0..6)
#pragma unroll 1
        for (int k = 0; k < 7; ++k) {
            float v0[5];
#pragma unroll
            for (int r = 0; r < 5; ++r) v0[r] = cl[0] * matbuf[k][r][lane];
#pragma unroll
            for (int l = 1; l < 5; ++l)
#pragma unroll
                for (int r = 0; r < 5; ++r)
                    v0[r] = fmaf(cl[l], matbuf[k][l * 5 + r][lane], v0[r]);
#pragma unroll
            for (int r = 0; r < 5; ++r) cl[r] = v0[r];
        }
        float* o = out + (size_t)row * 5;                  // vL stash (flat)
#pragma unroll
        for (int i = 0; i < 5; ++i) o[i] = cl[i];
    } else {
        // ---- right vec wave: vlast, site 781, pairs 389..375 desc,
        //      combine desc (slots 15..1, column form) ----
        v2f xz = xr2[391];                                 // {x782, x783}
        float vl[5], vn[5];
#pragma unroll
        for (int l = 0; l < 5; ++l)
            vl[l] = fmaf(xz[1], core_last[2 * l + 1] - core_last[2 * l], core_last[2 * l]);
        const float* cmL = cores_mid + (size_t)781 * 50;
#pragma unroll
        for (int l = 0; l < 5; ++l) {
            float a = 0.f;
#pragma unroll
            for (int r = 0; r < 5; ++r) {
                float m = fmaf(xz[0], cmL[l * 10 + 5 + r] - cmL[l * 10 + r], cmL[l * 10 + r]);
                a = fmaf(m, vl[r], a);
            }
            vn[l] = a;
        }
        v4f cv = {vn[0], vn[1], vn[2], vn[3]};
        float c4 = vn[4];

        v2f xc = xr2[390];
#pragma unroll 1
        for (int p = 389; p >= BWD_P0; --p) {              // transposed storage
            v2f nx = xr2[p];                               // x for pair p-1
            vecstepLM(cv, c4, pk + (size_t)p * PAIR_F, xc);
            xc = nx;
        }
        float u[5] = {cv[0], cv[1], cv[2], cv[3], c4};

        __syncthreads();   // b1: phase-1 slots (waves 15..8 at k=0..7)
#pragma unroll 1
        for (int k = 0; k < 8; ++k) {                      // u = M_slot @ u
            float v0[5];
#pragma unroll
            for (int i = 0; i < 5; ++i) {
                float a = matbuf[k][i * 5][lane] * u[0];
#pragma unroll
                for (int l = 1; l < 5; ++l)
                    a = fmaf(matbuf[k][i * 5 + l][lane], u[l], a);
                v0[i] = a;
            }
#pragma unroll
            for (int i = 0; i < 5; ++i) u[i] = v0[i];
        }
        __syncthreads();   // b2
        __syncthreads();   // b3: phase-2 slots (waves 7..1 at k=0..6)
#pragma unroll 1
        for (int k = 0; k < 7; ++k) {
            float v0[5];
#pragma unroll
            for (int i = 0; i < 5; ++i) {
                float a = matbuf[k][i * 5][lane] * u[0];
#pragma unroll
                for (int l = 1; l < 5; ++l)
                    a = fmaf(matbuf[k][i * 5 + l][lane], u[l], a);
                v0[i] = a;
            }
#pragma unroll
            for (int i = 0; i < 5; ++i) u[i] = v0[i];
        }
        float* o = out + WROFF + (size_t)row * 5;          // wR stash (flat)
#pragma unroll
        for (int i = 0; i < 5; ++i) o[i] = u[i];
    }
}

// ---- stage 2a: res[r] = vL . wR (res overwrites dead pk region of ws) ----
__global__ __launch_bounds__(256)
void finish_dot(const float* __restrict__ outF, float* __restrict__ res)
{
    int r = blockIdx.x * 256 + threadIdx.x;
    const float* vl = outF + (size_t)r * 5;
    const float* wr = outF + WROFF + (size_t)r * 5;
    float s = vl[0] * wr[0];
#pragma unroll
    for (int i = 1; i < 5; ++i) s = fmaf(vl[i], wr[i], s);
    res[r] = s;
}

// ---- stage 2b: out = res*fc_w + fc_b ----
__global__ __launch_bounds__(256)
void finish_out(const float* __restrict__ res, const float* __restrict__ fc_w,
                const float* __restrict__ fc_b, float* __restrict__ out)
{
    int r = blockIdx.x * 256 + threadIdx.x;
    float rv = res[r];
    float* o = out + (size_t)r * NOUT;
#pragma unroll
    for (int j = 0; j < NOUT; ++j) o[j] = fmaf(rv, fc_w[j], fc_b[j]);
}

extern "C" void kernel_launch(void* const* d_in, const int* in_sizes, int n_in,
                              void* d_out, int out_size, void* d_ws, size_t ws_size,
                              hipStream_t stream) {
    const float* x          = (const float*)d_in[0];
    const float* core_first = (const float*)d_in[1];
    const float* cores_mid  = (const float*)d_in[2];
    const float* core_last  = (const float*)d_in[3];
    const float* fc_w       = (const float*)d_in[4];
    const float* fc_b       = (const float*)d_in[5];
    float* out              = (float*)d_out;
    float* pk               = (float*)d_ws;   // 390*100*4 = 156,000 B
    float* res              = (float*)d_ws;   // reuses pk region (dead after main)

    hipLaunchKernelGGL(prepack_pairs, dim3((NPAIR * 100 + 255) / 256), dim3(256),
                       0, stream, cores_mid, pk);
    hipLaunchKernelGGL(mps_half_kernel, dim3(512), dim3(1024), 0, stream,
                       x, core_first, cores_mid, core_last, pk, out);
    hipLaunchKernelGGL(finish_dot, dim3(Bn / 256), dim3(256), 0, stream,
                       out, res);
    hipLaunchKernelGGL(finish_out, dim3(Bn / 256), dim3(256), 0, stream,
                       res, fc_w, fc_b, out);
}